// Round 1
// baseline (333.570 us; speedup 1.0000x reference)
//
#include <hip/hip_runtime.h>

// VQC: 8 qubits, dim=256 real amplitudes, 1 sample per wave64.
// Layout: amplitude index j (8 bits): j[1:0] = qubits 0,1 (register index v0..v3),
//         j[7:2] = qubits 2..7 (lane bits 0..5).
// v0: q0=0,q1=0 | v1: q0=1,q1=0 | v2: q0=0,q1=1 | v3: q0=1,q1=1

__device__ __forceinline__ float shx(float v, int m) { return __shfl_xor(v, m, 64); }

__global__ void vqc_kernel(const float* __restrict__ x,
                           const float* __restrict__ w,
                           float* __restrict__ out, int B)
{
    __shared__ float s_wc[32], s_ws[32];
    const int tid = threadIdx.x;
    if (tid < 32) {
        float sv, cv;
        __sincosf(0.5f * w[tid], &sv, &cv);
        s_wc[tid] = cv; s_ws[tid] = sv;
    }
    __syncthreads();

    const int lane = tid & 63;
    const int b = (blockIdx.x << 2) + (tid >> 6);
    if (b >= B) return;

    // ---- encode: H + RY(x) == product state; a(0)=(c-s)/sqrt2, a(1)=(c+s)/sqrt2
    float v0, v1, v2, v3;
    {
        const float* xb = x + b * 8;
        float f = 0.0625f;  // (1/sqrt2)^8
        #pragma unroll
        for (int q = 2; q < 8; ++q) {
            float sv, cv;
            __sincosf(0.5f * xb[q], &sv, &cv);
            f *= ((lane >> (q - 2)) & 1) ? (cv + sv) : (cv - sv);
        }
        float s0, c0, s1, c1;
        __sincosf(0.5f * xb[0], &s0, &c0);
        __sincosf(0.5f * xb[1], &s1, &c1);
        const float a00 = c0 - s0, a01 = c0 + s0;
        const float a10 = c1 - s1, a11 = c1 + s1;
        v0 = f * a00 * a10;
        v1 = f * a01 * a10;
        v2 = f * a00 * a11;
        v3 = f * a01 * a11;
    }

    // ---- 4 variational layers
    #pragma unroll
    for (int layer = 0; layer < 4; ++layer) {
        // CNOT(0,1): ctrl q0 (reg bit0), tgt q1 (reg bit1) -> swap v1<->v3
        { float t = v1; v1 = v3; v3 = t; }
        // CNOT(2,3): ctrl lane bit0, tgt lane bit1
        {
            const bool c = lane & 1;
            float p0 = shx(v0, 2), p1 = shx(v1, 2), p2 = shx(v2, 2), p3 = shx(v3, 2);
            v0 = c ? p0 : v0; v1 = c ? p1 : v1; v2 = c ? p2 : v2; v3 = c ? p3 : v3;
        }
        // CNOT(4,5): ctrl lane bit2, tgt lane bit3
        {
            const bool c = lane & 4;
            float p0 = shx(v0, 8), p1 = shx(v1, 8), p2 = shx(v2, 8), p3 = shx(v3, 8);
            v0 = c ? p0 : v0; v1 = c ? p1 : v1; v2 = c ? p2 : v2; v3 = c ? p3 : v3;
        }
        // CNOT(6,7): ctrl lane bit4, tgt lane bit5
        {
            const bool c = lane & 16;
            float p0 = shx(v0, 32), p1 = shx(v1, 32), p2 = shx(v2, 32), p3 = shx(v3, 32);
            v0 = c ? p0 : v0; v1 = c ? p1 : v1; v2 = c ? p2 : v2; v3 = c ? p3 : v3;
        }
        // CNOT(1,2): ctrl q1 (reg bit1 -> regs v2,v3), tgt q2 (lane bit0):
        // unconditional exchange across lane^1 for v2,v3 only
        v2 = shx(v2, 1);
        v3 = shx(v3, 1);
        // CNOT(3,4): ctrl lane bit1, tgt lane bit2
        {
            const bool c = lane & 2;
            float p0 = shx(v0, 4), p1 = shx(v1, 4), p2 = shx(v2, 4), p3 = shx(v3, 4);
            v0 = c ? p0 : v0; v1 = c ? p1 : v1; v2 = c ? p2 : v2; v3 = c ? p3 : v3;
        }
        // CNOT(5,6): ctrl lane bit3, tgt lane bit4
        {
            const bool c = lane & 8;
            float p0 = shx(v0, 16), p1 = shx(v1, 16), p2 = shx(v2, 16), p3 = shx(v3, 16);
            v0 = c ? p0 : v0; v1 = c ? p1 : v1; v2 = c ? p2 : v2; v3 = c ? p3 : v3;
        }
        // RY(q0): pairs (v0,v1),(v2,v3): new0=c*a0-s*a1; new1=s*a0+c*a1
        {
            const float c = s_wc[layer * 8 + 0], s = s_ws[layer * 8 + 0];
            float n0 = c * v0 - s * v1, n1 = s * v0 + c * v1;
            float n2 = c * v2 - s * v3, n3 = s * v2 + c * v3;
            v0 = n0; v1 = n1; v2 = n2; v3 = n3;
        }
        // RY(q1): pairs (v0,v2),(v1,v3)
        {
            const float c = s_wc[layer * 8 + 1], s = s_ws[layer * 8 + 1];
            float n0 = c * v0 - s * v2, n2 = s * v0 + c * v2;
            float n1 = c * v1 - s * v3, n3 = s * v1 + c * v3;
            v0 = n0; v1 = n1; v2 = n2; v3 = n3;
        }
        // RY(q2..q7): cross-lane; new = c*v + (bit? s : -s)*partner
        #pragma unroll
        for (int q = 2; q < 8; ++q) {
            const int m = 1 << (q - 2);
            const float c = s_wc[layer * 8 + q], s = s_ws[layer * 8 + q];
            const float ss = (lane & m) ? s : -s;
            float p0 = shx(v0, m), p1 = shx(v1, m), p2 = shx(v2, m), p3 = shx(v3, m);
            v0 = fmaf(ss, p0, c * v0);
            v1 = fmaf(ss, p1, c * v1);
            v2 = fmaf(ss, p2, c * v2);
            v3 = fmaf(ss, p3, c * v3);
        }
    }

    // ---- measurement: <Z_i> = sum_j (-1)^{bit_i(j)} |amp_j|^2
    const float p0 = v0 * v0, p1 = v1 * v1, p2 = v2 * v2, p3 = v3 * v3;
    float z0 = (p0 + p2) - (p1 + p3);   // q0 = reg bit0
    float z1 = (p0 + p1) - (p2 + p3);   // q1 = reg bit1
    float t  = (p0 + p1) + (p2 + p3);   // total per-lane prob -> WHT
    #pragma unroll
    for (int k = 0; k < 6; ++k) {
        const int m = 1 << k;
        z0 += shx(z0, m);
        z1 += shx(z1, m);
        float pt = shx(t, m);
        t = (lane & m) ? (pt - t) : (t + pt);
    }
    // after WHT: lane (1<<k) holds <Z_{2+k}>
    float* ob = out + b * 8;
    if (lane == 0) { ob[0] = z0; ob[1] = z1; }
    if (lane && !(lane & (lane - 1))) {
        ob[1 + __ffs(lane)] = t;   // lane=1->out[2] ... lane=32->out[7]
    }
}

extern "C" void kernel_launch(void* const* d_in, const int* in_sizes, int n_in,
                              void* d_out, int out_size, void* d_ws, size_t ws_size,
                              hipStream_t stream) {
    const float* x = (const float*)d_in[0];
    const float* w = (const float*)d_in[1];
    float* out = (float*)d_out;
    const int B = in_sizes[0] / 8;           // 131072
    const int blocks = (B + 3) / 4;          // 4 samples (waves) per 256-thread block
    hipLaunchKernelGGL(vqc_kernel, dim3(blocks), dim3(256), 0, stream, x, w, out, B);
}

// Round 6
// 131.201 us; speedup vs baseline: 2.5424x; 2.5424x over previous
//
#include <hip/hip_runtime.h>

// VQC, 8 qubits, 256 real amplitudes. One sample per QUAD (4 lanes).
// Amplitude index j (8 bits): j[5:0] = register index (qubits 0..5),
// j[6] = lane bit0 (qubit 6), j[7] = lane bit1 (qubit 7).
// All cross-lane movement is quad_perm DPP (VALU pipe) -> zero DS-pipe usage.

#define DPP_XOR1   0xB1  // quad_perm [1,0,3,2]
#define DPP_XOR2   0x4E  // quad_perm [2,3,0,1]
#define DPP_CNOT67 0x6C  // quad_perm [0,3,2,1]: lanes with bit0=1 swap across bit1

template<int CTRL>
__device__ __forceinline__ float dppf(float v) {
    return __int_as_float(__builtin_amdgcn_mov_dpp(__float_as_int(v), CTRL, 0xF, 0xF, true));
}

__global__ void __launch_bounds__(256) vqc_kernel(const float* __restrict__ x,
                                                  const float* __restrict__ w,
                                                  float* __restrict__ out, int B)
{
    const int tid  = blockIdx.x * blockDim.x + threadIdx.x;
    const int k    = tid & 3;        // lane-in-quad: bit0 -> q6, bit1 -> q7
    const int s    = tid >> 2;       // sample index, one per quad
    if (s >= B) return;

    // ---- load the sample's 8 angles (all 4 lanes load the same 32B; L1 broadcast)
    const float4 x0 = *(const float4*)(x + s * 8);
    const float4 x1 = *(const float4*)(x + s * 8 + 4);
    const float ang[8] = {x0.x, x0.y, x0.z, x0.w, x1.x, x1.y, x1.z, x1.w};

    // H + RY(x) on |0> is a product state: u(0) = (c-s), u(1) = (c+s), x 1/sqrt2 per qubit
    float u0[8], u1[8];
    #pragma unroll
    for (int q = 0; q < 8; ++q) {
        float sv, cv; __sincosf(0.5f * ang[q], &sv, &cv);
        u0[q] = cv - sv; u1[q] = cv + sv;
    }
    // per-lane factor for qubits 6,7 and the global (1/sqrt2)^8 = 1/16
    const float fl = 0.0625f * ((k & 1) ? u1[6] : u0[6]) * ((k & 2) ? u1[7] : u0[7]);

    // product tree over register qubits 0..5 -> a[64]
    float a[64];
    a[0] = fl * u0[0];
    a[1] = fl * u1[0];
    #pragma unroll
    for (int q = 1; q < 6; ++q) {
        const int h = 1 << q;
        #pragma unroll
        for (int r = h - 1; r >= 0; --r) {
            const float base = a[r];
            a[r + h] = base * u1[q];
            a[r]     = base * u0[q];
        }
    }

    // ---- 4 variational layers
    #pragma unroll
    for (int layer = 0; layer < 4; ++layer) {
        // weight sincos (uniform across lanes; w loads scalarize)
        float wc[8], ws[8];
        #pragma unroll
        for (int q = 0; q < 8; ++q)
            __sincosf(0.5f * w[layer * 8 + q], &ws[q], &wc[q]);

        // CNOT(0,1): ctrl reg bit0, tgt reg bit1 -> register rename (free)
        #pragma unroll
        for (int r = 0; r < 64; ++r)
            if ((r & 1) && !(r & 2)) { float t = a[r]; a[r] = a[r | 2]; a[r | 2] = t; }
        // CNOT(2,3)
        #pragma unroll
        for (int r = 0; r < 64; ++r)
            if ((r & 4) && !(r & 8)) { float t = a[r]; a[r] = a[r | 8]; a[r | 8] = t; }
        // CNOT(4,5)
        #pragma unroll
        for (int r = 0; r < 64; ++r)
            if ((r & 16) && !(r & 32)) { float t = a[r]; a[r] = a[r | 32]; a[r | 32] = t; }
        // CNOT(6,7): ctrl lane bit0, tgt lane bit1 -> one quad_perm, no select
        #pragma unroll
        for (int r = 0; r < 64; ++r) a[r] = dppf<DPP_CNOT67>(a[r]);
        // CNOT(1,2)
        #pragma unroll
        for (int r = 0; r < 64; ++r)
            if ((r & 2) && !(r & 4)) { float t = a[r]; a[r] = a[r | 4]; a[r | 4] = t; }
        // CNOT(3,4)
        #pragma unroll
        for (int r = 0; r < 64; ++r)
            if ((r & 8) && !(r & 16)) { float t = a[r]; a[r] = a[r | 16]; a[r | 16] = t; }
        // CNOT(5,6): ctrl reg bit5, tgt lane bit0 -> quad_perm xor1 on regs 32..63
        #pragma unroll
        for (int r = 32; r < 64; ++r) a[r] = dppf<DPP_XOR1>(a[r]);

        // RY on register qubits 0..5
        #pragma unroll
        for (int q = 0; q < 6; ++q) {
            const int m = 1 << q;
            #pragma unroll
            for (int r = 0; r < 64; ++r) {
                if (!(r & m)) {
                    const float lo = a[r], hi = a[r | m];
                    a[r]     = fmaf(-ws[q], hi, wc[q] * lo);
                    a[r | m] = fmaf( ws[q], lo, wc[q] * hi);
                }
            }
        }
        // RY(q6): partner across lane bit0
        {
            const float ss = (k & 1) ? ws[6] : -ws[6];
            #pragma unroll
            for (int r = 0; r < 64; ++r) {
                const float p = dppf<DPP_XOR1>(a[r]);
                a[r] = fmaf(ss, p, wc[6] * a[r]);
            }
        }
        // RY(q7): partner across lane bit1
        {
            const float ss = (k & 2) ? ws[7] : -ws[7];
            #pragma unroll
            for (int r = 0; r < 64; ++r) {
                const float p = dppf<DPP_XOR2>(a[r]);
                a[r] = fmaf(ss, p, wc[7] * a[r]);
            }
        }
    }

    // ---- measurement: <Z_i> = sum_j (-1)^{bit_i(j)} amp_j^2
    // square in place, then a halving even/odd tree with no temp arrays
    #pragma unroll
    for (int r = 0; r < 64; ++r) a[r] = a[r] * a[r];

    float z[8];
    #pragma unroll
    for (int q = 0; q < 6; ++q) {
        const int n = 64 >> q;          // live prefix length of a[]
        float zz = 0.0f;
        #pragma unroll
        for (int i = 0; i < n / 2; ++i) {
            const float e = a[2 * i], o = a[2 * i + 1];
            zz  += e - o;
            a[i] = e + o;
        }
        z[q] = zz;
    }
    const float t = a[0];               // per-lane total probability

    // quad reductions (DPP): z0..z5 sum over 4 lanes
    #pragma unroll
    for (int q = 0; q < 6; ++q) {
        z[q] += dppf<DPP_XOR1>(z[q]);
        z[q] += dppf<DPP_XOR2>(z[q]);
    }
    // z6 = P(l0=0) - P(l0=1), z7 = P(l1=0) - P(l1=1)
    {
        const float v  = dppf<DPP_XOR1>(t);
        const float d6 = (k & 1) ? (v - t) : (t - v);
        z[6] = d6 + dppf<DPP_XOR2>(d6);
        const float wv = dppf<DPP_XOR2>(t);
        const float d7 = (k & 2) ? (wv - t) : (t - wv);
        z[7] = d7 + dppf<DPP_XOR1>(d7);
    }

    // store: lane k of the quad writes out[8s+2k], out[8s+2k+1] (8B/lane, coalesced)
    const float lo = (k == 0) ? z[0] : (k == 1) ? z[2] : (k == 2) ? z[4] : z[6];
    const float hi = (k == 0) ? z[1] : (k == 1) ? z[3] : (k == 2) ? z[5] : z[7];
    *(float2*)(out + s * 8 + k * 2) = make_float2(lo, hi);
}

extern "C" void kernel_launch(void* const* d_in, const int* in_sizes, int n_in,
                              void* d_out, int out_size, void* d_ws, size_t ws_size,
                              hipStream_t stream) {
    const float* x = (const float*)d_in[0];
    const float* w = (const float*)d_in[1];
    float* out = (float*)d_out;
    const int B = in_sizes[0] / 8;                  // 131072 samples
    const int total_threads = B * 4;                // 4 lanes per sample
    const int blocks = (total_threads + 255) / 256;
    hipLaunchKernelGGL(vqc_kernel, dim3(blocks), dim3(256), 0, stream, x, w, out, B);
}

// Round 13
// 104.756 us; speedup vs baseline: 3.1843x; 1.2524x over previous
//
#include <hip/hip_runtime.h>

// VQC, 8 qubits, 256 real fp32 amplitudes. One sample per QUAD (4 lanes).
// Amplitude index j (8 bits): j[4:0]+j[5] -> f32x2 array: a2[i] packs
// (q5=0, q5=1) halves; i bits 0..4 = qubits 0..4; lane bit0 = q6, bit1 = q7.
// Cross-lane = quad_perm DPP (VALU pipe). Rotations use the tan-form
// RY = cos * [[1,-t],[t,1]] (cos factors folded into one global scale,
// lane-uniform since weights are shared) issued as v_pk_fma_f32 (2 FMA/instr).

typedef float f32x2 __attribute__((ext_vector_type(2)));

#define DPP_XOR1   0xB1  // quad_perm [1,0,3,2]
#define DPP_XOR2   0x4E  // quad_perm [2,3,0,1]
#define DPP_CNOT67 0x6C  // quad_perm [0,3,2,1]

template<int CTRL>
__device__ __forceinline__ float dppf(float v) {
    return __int_as_float(__builtin_amdgcn_mov_dpp(__float_as_int(v), CTRL, 0xF, 0xF, true));
}
template<int CTRL>
__device__ __forceinline__ f32x2 dpp2(f32x2 v) {
    f32x2 r;
    r.x = dppf<CTRL>(v.x);
    r.y = dppf<CTRL>(v.y);
    return r;
}

// ---- packed FP32 fma variants (tpm = (-t, +t)) ----
__device__ __forceinline__ f32x2 pk_fma(f32x2 a, f32x2 b, f32x2 c) {
    f32x2 d;
    asm("v_pk_fma_f32 %0, %1, %2, %3 op_sel:[0,0,0] op_sel_hi:[1,1,1]"
        : "=v"(d) : "v"(a), "v"(b), "v"(c));
    return d;
}
// d = (-t)*b + c   (both halves use tpm.lo = -t)
__device__ __forceinline__ f32x2 pk_fma_mt(f32x2 tpm, f32x2 b, f32x2 c) {
    f32x2 d;
    asm("v_pk_fma_f32 %0, %1, %2, %3 op_sel:[0,0,0] op_sel_hi:[0,1,1]"
        : "=v"(d) : "v"(tpm), "v"(b), "v"(c));
    return d;
}
// d = (+t)*b + c   (both halves use tpm.hi = +t)
__device__ __forceinline__ f32x2 pk_fma_pt(f32x2 tpm, f32x2 b, f32x2 c) {
    f32x2 d;
    asm("v_pk_fma_f32 %0, %1, %2, %3 op_sel:[1,0,0] op_sel_hi:[1,1,1]"
        : "=v"(d) : "v"(tpm), "v"(b), "v"(c));
    return d;
}
// RY on the packed axis: d.lo = -t*v.hi + v.lo ; d.hi = +t*v.lo + v.hi
__device__ __forceinline__ f32x2 pk_ry_packed(f32x2 tpm, f32x2 v) {
    f32x2 d;
    asm("v_pk_fma_f32 %0, %1, %2, %3 op_sel:[0,1,0] op_sel_hi:[1,0,1]"
        : "=v"(d) : "v"(tpm), "v"(v), "v"(v));
    return d;
}

// sin/cos of theta/2 via hw v_sin/v_cos (revolutions); |theta|<=~5.3 is in range
__device__ __forceinline__ void sc_half(float theta, float* s, float* c) {
    const float rev = theta * 0.07957747154594767f;  // (theta/2) / (2*pi)
    *s = __builtin_amdgcn_sinf(rev);
    *c = __builtin_amdgcn_cosf(rev);
}

__global__ void __launch_bounds__(256, 4) vqc_kernel(const float* __restrict__ x,
                                                     const float* __restrict__ w,
                                                     float* __restrict__ out, int B)
{
    const int tid = blockIdx.x * blockDim.x + threadIdx.x;
    const int k   = tid & 3;        // lane-in-quad: bit0 -> q6, bit1 -> q7
    const int s   = tid >> 2;       // sample index
    if (s >= B) return;

    // ---- encode: H+RY(x) product state. u(0)=(c-s), u(1)=(c+s), /sqrt2 per qubit
    const float4 x0 = *(const float4*)(x + s * 8);
    const float4 x1 = *(const float4*)(x + s * 8 + 4);
    const float ang[8] = {x0.x, x0.y, x0.z, x0.w, x1.x, x1.y, x1.z, x1.w};
    float u0[8], u1[8];
    #pragma unroll
    for (int q = 0; q < 8; ++q) {
        float sv, cv; sc_half(ang[q], &sv, &cv);
        u0[q] = cv - sv; u1[q] = cv + sv;
    }
    const float fl = 0.0625f * ((k & 1) ? u1[6] : u0[6]) * ((k & 2) ? u1[7] : u0[7]);

    // product tree over qubits 0..4 (scalar), then pack q5 into f32x2 halves
    float t32[32];
    t32[0] = fl * u0[0];
    t32[1] = fl * u1[0];
    #pragma unroll
    for (int q = 1; q < 5; ++q) {
        const int h = 1 << q;
        #pragma unroll
        for (int r = h - 1; r >= 0; --r) {
            const float base = t32[r];
            t32[r + h] = base * u1[q];
            t32[r]     = base * u0[q];
        }
    }
    f32x2 a2[32];
    #pragma unroll
    for (int i = 0; i < 32; ++i) {
        a2[i].x = t32[i] * u0[5];
        a2[i].y = t32[i] * u1[5];
    }

    // ---- per-gate tangents for the 32 variational RYs (lane-uniform)
    float tl[32];
    float prodc = 1.0f;
    #pragma unroll
    for (int g = 0; g < 32; ++g) {
        float sv, cv; sc_half(w[g], &sv, &cv);
        tl[g] = __fdividef(sv, cv);
        prodc *= cv;
    }
    const float C2 = prodc * prodc;   // fold all cos factors into final <Z>

    // ---- 4 variational layers
    #pragma unroll
    for (int layer = 0; layer < 4; ++layer) {
        const float* tw = tl + layer * 8;

        // CNOT(0,1): ctrl bit0, tgt bit1 (f2-index rename, free)
        #pragma unroll
        for (int i = 0; i < 32; ++i)
            if ((i & 1) && !(i & 2)) { f32x2 t = a2[i]; a2[i] = a2[i | 2]; a2[i | 2] = t; }
        // CNOT(2,3)
        #pragma unroll
        for (int i = 0; i < 32; ++i)
            if ((i & 4) && !(i & 8)) { f32x2 t = a2[i]; a2[i] = a2[i | 8]; a2[i | 8] = t; }
        // CNOT(4,5): ctrl bit4, tgt q5 (packed half) -> component swap (rename)
        #pragma unroll
        for (int i = 16; i < 32; ++i) { const f32x2 v = a2[i]; a2[i].x = v.y; a2[i].y = v.x; }
        // CNOT(6,7): ctrl lane bit0, tgt lane bit1 -> quad_perm both halves
        #pragma unroll
        for (int i = 0; i < 32; ++i) a2[i] = dpp2<DPP_CNOT67>(a2[i]);
        // CNOT(1,2)
        #pragma unroll
        for (int i = 0; i < 32; ++i)
            if ((i & 2) && !(i & 4)) { f32x2 t = a2[i]; a2[i] = a2[i | 4]; a2[i | 4] = t; }
        // CNOT(3,4)
        #pragma unroll
        for (int i = 0; i < 32; ++i)
            if ((i & 8) && !(i & 16)) { f32x2 t = a2[i]; a2[i] = a2[i | 16]; a2[i | 16] = t; }
        // CNOT(5,6): ctrl q5 (hi half), tgt q6 (lane bit0) -> dpp the .y only
        #pragma unroll
        for (int i = 0; i < 32; ++i) a2[i].y = dppf<DPP_XOR1>(a2[i].y);

        // RY q0..q4 (tan form, packed): A' = A - t*B ; B' = B + t*A
        #pragma unroll
        for (int q = 0; q < 5; ++q) {
            const float t = tw[q];
            const f32x2 tpm = {-t, t};
            const int m = 1 << q;
            #pragma unroll
            for (int i = 0; i < 32; ++i) {
                if (!(i & m)) {
                    const f32x2 A = a2[i], Bv = a2[i | m];
                    a2[i]     = pk_fma_mt(tpm, Bv, A);
                    a2[i | m] = pk_fma_pt(tpm, A, Bv);
                }
            }
        }
        // RY q5 (packed axis): one pk_fma with op_sel half-swap
        {
            const float t = tw[5];
            const f32x2 tpm = {-t, t};
            #pragma unroll
            for (int i = 0; i < 32; ++i) a2[i] = pk_ry_packed(tpm, a2[i]);
        }
        // RY q6: partner across lane bit0; sign by lane bit
        {
            const float st = (k & 1) ? tw[6] : -tw[6];
            const f32x2 st2 = {st, st};
            #pragma unroll
            for (int i = 0; i < 32; ++i)
                a2[i] = pk_fma(st2, dpp2<DPP_XOR1>(a2[i]), a2[i]);
        }
        // RY q7: partner across lane bit1
        {
            const float st = (k & 2) ? tw[7] : -tw[7];
            const f32x2 st2 = {st, st};
            #pragma unroll
            for (int i = 0; i < 32; ++i)
                a2[i] = pk_fma(st2, dpp2<DPP_XOR2>(a2[i]), a2[i]);
        }
    }

    // ---- measurement: <Z_i> = sum_j (-1)^{bit_i(j)} amp_j^2, then scale by C2
    float s32[32], d5 = 0.0f;
    #pragma unroll
    for (int i = 0; i < 32; ++i) {
        const float px = a2[i].x * a2[i].x;
        const float py = a2[i].y * a2[i].y;
        s32[i] = px + py;
        d5 += px - py;
    }
    float z[8];
    #pragma unroll
    for (int q = 0; q < 5; ++q) {        // tree over f2-index bits = qubits 0..4
        const int n = 32 >> q;
        float acc = 0.0f;
        #pragma unroll
        for (int i = 0; i < n / 2; ++i) {
            const float e = s32[2 * i], o = s32[2 * i + 1];
            acc += e - o;
            s32[i] = e + o;
        }
        z[q] = acc;
    }
    z[5] = d5;
    const float t = s32[0];              // per-lane total probability

    // quad sums for z0..z5
    #pragma unroll
    for (int q = 0; q < 6; ++q) {
        z[q] += dppf<DPP_XOR1>(z[q]);
        z[q] += dppf<DPP_XOR2>(z[q]);
    }
    // z6 = P(q6=0)-P(q6=1), z7 = P(q7=0)-P(q7=1)
    {
        const float v  = dppf<DPP_XOR1>(t);
        const float d6 = (k & 1) ? (v - t) : (t - v);
        z[6] = d6 + dppf<DPP_XOR2>(d6);
        const float wv = dppf<DPP_XOR2>(t);
        const float d7 = (k & 2) ? (wv - t) : (t - wv);
        z[7] = d7 + dppf<DPP_XOR1>(d7);
    }
    #pragma unroll
    for (int j = 0; j < 8; ++j) z[j] *= C2;

    // store: lane k writes out[8s+2k], out[8s+2k+1] (8B/lane, coalesced)
    const float lo = (k == 0) ? z[0] : (k == 1) ? z[2] : (k == 2) ? z[4] : z[6];
    const float hi = (k == 0) ? z[1] : (k == 1) ? z[3] : (k == 2) ? z[5] : z[7];
    f32x2 o2; o2.x = lo; o2.y = hi;
    *(f32x2*)(out + s * 8 + k * 2) = o2;
}

extern "C" void kernel_launch(void* const* d_in, const int* in_sizes, int n_in,
                              void* d_out, int out_size, void* d_ws, size_t ws_size,
                              hipStream_t stream) {
    const float* x = (const float*)d_in[0];
    const float* w = (const float*)d_in[1];
    float* out = (float*)d_out;
    const int B = in_sizes[0] / 8;                  // 131072 samples
    const int total_threads = B * 4;                // 4 lanes per sample
    const int blocks = (total_threads + 255) / 256;
    hipLaunchKernelGGL(vqc_kernel, dim3(blocks), dim3(256), 0, stream, x, w, out, B);
}